// Round 1
// baseline (181.857 us; speedup 1.0000x reference)
//
#include <hip/hip_runtime.h>
#include <math.h>

#define NSIG 1000
#define NP   3997      // interp points = FFT length
#define NW   995       // n_windows
#define WIN  20
#define STEPW 4
#define BATCH 4

// ws layout (bytes):
//   ks   : BATCH*NP floats        @ 0       (63952)
//   tw   : NP float2              @ 64000   (31976)
//   S    : BATCH*NP float2        @ 96000   (127904)
//   rmax : BATCH uint             @ 224000

__device__ __forceinline__ double interp_at(const float* __restrict__ s, int p) {
    int i0 = p >> 2;
    int si = p & 3;
    double ss = 0.25 * (double)si;
    const double A = -0.75;
    double d0 = ss + 1.0;
    double w0 = ((A * d0 - 5.0 * A) * d0 + 8.0 * A) * d0 - 4.0 * A;
    double w1 = ((A + 2.0) * ss - (A + 3.0)) * ss * ss + 1.0;
    double d2 = 1.0 - ss;
    double w2 = ((A + 2.0) * d2 - (A + 3.0)) * d2 * d2 + 1.0;
    double d3 = 2.0 - ss;
    double w3 = ((A * d3 - 5.0 * A) * d3 + 8.0 * A) * d3 - 4.0 * A;
    int im1 = i0 - 1; if (im1 < 0) im1 = 0;
    int ip1 = i0 + 1; if (ip1 > NSIG - 1) ip1 = NSIG - 1;
    int ip2 = i0 + 2; if (ip2 > NSIG - 1) ip2 = NSIG - 1;
    return w0 * (double)s[im1] + w1 * (double)s[i0] +
           w2 * (double)s[ip1] + w3 * (double)s[ip2];
}

// K1: interp -> row min -> kernel mix -> ks (float)
__global__ void prep_kernel(const float* __restrict__ sig,
                            const float* __restrict__ gamma_raw,
                            float* __restrict__ ks) {
    __shared__ double red[256];
    int b = blockIdx.x;
    const float* srow = sig + b * NSIG;
    double lmin = 1e300;
    for (int p = threadIdx.x; p < NP; p += 256)
        lmin = fmin(lmin, interp_at(srow, p));
    red[threadIdx.x] = lmin;
    __syncthreads();
    for (int s = 128; s > 0; s >>= 1) {
        if (threadIdx.x < s)
            red[threadIdx.x] = fmin(red[threadIdx.x], red[threadIdx.x + s]);
        __syncthreads();
    }
    double m = fmin(red[0], 0.0);
    double g0r = (double)gamma_raw[0], g1r = (double)gamma_raw[1];
    double mx = fmax(g0r, g1r);
    double e0 = exp(g0r - mx), e1 = exp(g1r - mx);
    double inv = 1.0 / (e0 + e1);
    double g0 = e0 * inv, g1 = e1 * inv;
    for (int p = threadIdx.x; p < NP; p += 256) {
        double x = interp_at(srow, p) - m;
        double poly = (x + 1.3) * (x + 1.3);
        double gauss = exp(-0.5 * (x - 0.7) * (x - 0.7));
        ks[b * NP + p] = (float)(g0 * poly + g1 * gauss);
    }
}

// K2: twiddle table (double-computed, float2 stored) + zero result-max
__global__ void twiddle_kernel(float2* __restrict__ tw,
                               unsigned int* __restrict__ rmax) {
    int m = blockIdx.x * 256 + threadIdx.x;
    if (m < NP) {
        double ang = -6.283185307179586476925286766559 * ((double)m / (double)NP);
        tw[m] = make_float2((float)cos(ang), (float)sin(ang));
    }
    if (blockIdx.x == 0 && threadIdx.x < BATCH) rmax[threadIdx.x] = 0u;
}

// K3: full DFT S[b,k] = sum_t ks[t] * tw[(k*t) mod NP], double accumulation
__global__ __launch_bounds__(256) void dft_kernel(const float* __restrict__ ks,
                                                  const float2* __restrict__ tw,
                                                  float2* __restrict__ S) {
    __shared__ float2 ltw[NP];
    __shared__ float  lks[NP];
    __shared__ double2 red[256];
    int b = blockIdx.y;
    int kbase = blockIdx.x * 64;
    for (int i = threadIdx.x; i < NP; i += 256) {
        ltw[i] = tw[i];
        lks[i] = ks[b * NP + i];
    }
    __syncthreads();
    int kk = threadIdx.x & 63;
    int tc = threadIdx.x >> 6;
    int k = kbase + kk;
    double sr = 0.0, sim = 0.0;
    if (k < NP) {
        int t0 = tc * 1000;
        int t1 = t0 + 1000; if (t1 > NP) t1 = NP;
        int idx = (k * t0) % NP;   // fits int32: k*t0 <= 3996*3000
        for (int t = t0; t < t1; ++t) {
            float kv = lks[t];
            float2 w = ltw[idx];
            sr  += (double)kv * (double)w.x;
            sim += (double)kv * (double)w.y;
            idx += k; if (idx >= NP) idx -= NP;
        }
    }
    red[threadIdx.x] = make_double2(sr, sim);
    __syncthreads();
    if (tc == 0 && k < NP) {
        double2 a = red[kk], b2 = red[kk + 64], c = red[kk + 128], d = red[kk + 192];
        S[b * NP + k] = make_float2((float)(a.x + b2.x + c.x + d.x),
                                    (float)(a.y + b2.y + c.y + d.y));
    }
}

// K4: per (b,w): 20-term windowed DFT, M, M1=|S-W|, strong mask, result, row max
__global__ __launch_bounds__(256) void window_kernel(
        const float* __restrict__ ks, const float2* __restrict__ tw,
        const float2* __restrict__ S, const float* __restrict__ alpha_p,
        float* __restrict__ out, unsigned int* __restrict__ rmax) {
    __shared__ float2 ltw[NP];
    __shared__ float red[256];
    __shared__ float ksw[WIN];
    int b = blockIdx.y;
    int w = blockIdx.x;
    int start = w * STEPW;
    for (int i = threadIdx.x; i < NP; i += 256) ltw[i] = tw[i];
    if (threadIdx.x < WIN) ksw[threadIdx.x] = ks[b * NP + start + threadIdx.x];
    __syncthreads();
    float alpha = *alpha_p;

    float Mv[16], M1v[16];
    float lmax = 0.f;
    #pragma unroll
    for (int c = 0; c < 16; ++c) {
        int k = threadIdx.x + c * 256;
        float Mc = 0.f, M1c = 0.f;
        if (k < NP) {
            int idx = (k * start) % NP;   // <= 3996*3976, fits int32
            float wr = 0.f, wi = 0.f;
            #pragma unroll
            for (int j = 0; j < WIN; ++j) {
                float2 t = ltw[idx];
                wr = fmaf(ksw[j], t.x, wr);
                wi = fmaf(ksw[j], t.y, wi);
                idx += k; if (idx >= NP) idx -= NP;
            }
            Mc = sqrtf(wr * wr + wi * wi);
            float2 Sv = S[b * NP + k];
            float dr = Sv.x - wr, di = Sv.y - wi;
            M1c = sqrtf(dr * dr + di * di);
            lmax = fmaxf(lmax, Mc);
        }
        Mv[c] = Mc; M1v[c] = M1c;
    }
    red[threadIdx.x] = lmax;
    __syncthreads();
    for (int s = 128; s > 0; s >>= 1) {
        if (threadIdx.x < s)
            red[threadIdx.x] = fmaxf(red[threadIdx.x], red[threadIdx.x + s]);
        __syncthreads();
    }
    float cutoff = red[0] * alpha;
    __syncthreads();

    float rlmax = 0.f;
    size_t base = ((size_t)(b * NW + w)) * NP;
    #pragma unroll
    for (int c = 0; c < 16; ++c) {
        int k = threadIdx.x + c * 256;
        if (k < NP) {
            float M = Mv[c];
            float res = 0.f;
            if (M > cutoff) res = fminf(M, M1v[c] * M);  // strong=1 path; else 0
            out[base + k] = res;
            rlmax = fmaxf(rlmax, res);
        }
    }
    red[threadIdx.x] = rlmax;
    __syncthreads();
    for (int s = 128; s > 0; s >>= 1) {
        if (threadIdx.x < s)
            red[threadIdx.x] = fmaxf(red[threadIdx.x], red[threadIdx.x + s]);
        __syncthreads();
    }
    if (threadIdx.x == 0) atomicMax(&rmax[b], __float_as_uint(red[0]));
}

// K5: final threshold result * (result > beta*max)
__global__ void thresh_kernel(float* __restrict__ out,
                              const unsigned int* __restrict__ rmax,
                              const float* __restrict__ beta_p) {
    int b = blockIdx.y;
    size_t i = (size_t)blockIdx.x * 256 + threadIdx.x;
    const size_t n = (size_t)NW * NP;
    if (i < n) {
        float thr = (*beta_p) * __uint_as_float(rmax[b]);
        float* p = out + (size_t)b * n + i;
        float v = *p;
        if (v != 0.0f && !(v > thr)) *p = 0.f;
    }
}

extern "C" void kernel_launch(void* const* d_in, const int* in_sizes, int n_in,
                              void* d_out, int out_size, void* d_ws, size_t ws_size,
                              hipStream_t stream) {
    const float* sig       = (const float*)d_in[0];
    const float* alpha_p   = (const float*)d_in[1];
    const float* beta_p    = (const float*)d_in[2];
    const float* gamma_raw = (const float*)d_in[3];
    char* ws = (char*)d_ws;
    float*        ks   = (float*)(ws + 0);
    float2*       tw   = (float2*)(ws + 64000);
    float2*       S    = (float2*)(ws + 96000);
    unsigned int* rmax = (unsigned int*)(ws + 224000);
    float* out = (float*)d_out;

    hipLaunchKernelGGL(prep_kernel,    dim3(BATCH),    dim3(256), 0, stream, sig, gamma_raw, ks);
    hipLaunchKernelGGL(twiddle_kernel, dim3(16),       dim3(256), 0, stream, tw, rmax);
    hipLaunchKernelGGL(dft_kernel,     dim3(63, BATCH),dim3(256), 0, stream, ks, tw, S);
    hipLaunchKernelGGL(window_kernel,  dim3(NW, BATCH),dim3(256), 0, stream, ks, tw, S, alpha_p, out, rmax);
    hipLaunchKernelGGL(thresh_kernel,  dim3((NW * NP + 255) / 256, BATCH), dim3(256), 0, stream,
                       out, rmax, beta_p);
}

// Round 2
// 109.573 us; speedup vs baseline: 1.6597x; 1.6597x over previous
//
#include <hip/hip_runtime.h>
#include <math.h>

#define NSIG 1000
#define NP   3997      // interp points = FFT length (odd)
#define KHALF 1999     // distinct spectrum bins: k = 0..1998 (rest mirror)
#define NW   995       // n_windows
#define WIN  20
#define STEPW 4
#define BATCH 4

// ws layout (bytes):
//   ks   : BATCH*NP floats        @ 0       (63952)
//   tw   : NP float2              @ 64000   (31976)
//   S    : BATCH*NP float2        @ 96000   (only first KHALF/row used)
//   rmax : BATCH uint             @ 224000

__device__ __forceinline__ double interp_at(const float* __restrict__ s, int p) {
    int i0 = p >> 2;
    int si = p & 3;
    double ss = 0.25 * (double)si;
    const double A = -0.75;
    double d0 = ss + 1.0;
    double w0 = ((A * d0 - 5.0 * A) * d0 + 8.0 * A) * d0 - 4.0 * A;
    double w1 = ((A + 2.0) * ss - (A + 3.0)) * ss * ss + 1.0;
    double d2 = 1.0 - ss;
    double w2 = ((A + 2.0) * d2 - (A + 3.0)) * d2 * d2 + 1.0;
    double d3 = 2.0 - ss;
    double w3 = ((A * d3 - 5.0 * A) * d3 + 8.0 * A) * d3 - 4.0 * A;
    int im1 = i0 - 1; if (im1 < 0) im1 = 0;
    int ip1 = i0 + 1; if (ip1 > NSIG - 1) ip1 = NSIG - 1;
    int ip2 = i0 + 2; if (ip2 > NSIG - 1) ip2 = NSIG - 1;
    return w0 * (double)s[im1] + w1 * (double)s[i0] +
           w2 * (double)s[ip1] + w3 * (double)s[ip2];
}

// K1: interp -> row min -> kernel mix -> ks (float)
__global__ void prep_kernel(const float* __restrict__ sig,
                            const float* __restrict__ gamma_raw,
                            float* __restrict__ ks) {
    __shared__ double red[256];
    int b = blockIdx.x;
    const float* srow = sig + b * NSIG;
    double lmin = 1e300;
    for (int p = threadIdx.x; p < NP; p += 256)
        lmin = fmin(lmin, interp_at(srow, p));
    red[threadIdx.x] = lmin;
    __syncthreads();
    for (int s = 128; s > 0; s >>= 1) {
        if (threadIdx.x < s)
            red[threadIdx.x] = fmin(red[threadIdx.x], red[threadIdx.x + s]);
        __syncthreads();
    }
    double m = fmin(red[0], 0.0);
    double g0r = (double)gamma_raw[0], g1r = (double)gamma_raw[1];
    double mx = fmax(g0r, g1r);
    double e0 = exp(g0r - mx), e1 = exp(g1r - mx);
    double inv = 1.0 / (e0 + e1);
    double g0 = e0 * inv, g1 = e1 * inv;
    for (int p = threadIdx.x; p < NP; p += 256) {
        double x = interp_at(srow, p) - m;
        double poly = (x + 1.3) * (x + 1.3);
        double gauss = exp(-0.5 * (x - 0.7) * (x - 0.7));
        ks[b * NP + p] = (float)(g0 * poly + g1 * gauss);
    }
}

// K2: twiddle table (double-computed, float2 stored) + zero result-max
__global__ void twiddle_kernel(float2* __restrict__ tw,
                               unsigned int* __restrict__ rmax) {
    int m = blockIdx.x * 256 + threadIdx.x;
    if (m < NP) {
        double ang = -6.283185307179586476925286766559 * ((double)m / (double)NP);
        tw[m] = make_float2((float)cos(ang), (float)sin(ang));
    }
    if (blockIdx.x == 0 && threadIdx.x < BATCH) rmax[threadIdx.x] = 0u;
}

// K3: full DFT, half spectrum only. Grid (125, BATCH), 256 thr = 16 k x 16 t-chunks.
// Double-precision phase recurrence (no twiddle table needed).
__global__ __launch_bounds__(256) void dft_kernel(const float* __restrict__ ks,
                                                  double2* __restrict__ redws, // unused
                                                  float2* __restrict__ S) {
    __shared__ float  lks[NP];
    __shared__ double2 red[256];
    int b = blockIdx.y;
    int tid = threadIdx.x;
    int kk = tid & 15;
    int tc = tid >> 4;
    int k = blockIdx.x * 16 + kk;
    for (int i = tid; i < NP; i += 256) lks[i] = ks[b * NP + i];
    __syncthreads();

    double sr = 0.0, si = 0.0;
    if (k < KHALF) {
        int t0 = tc * 250;
        int t1 = t0 + 250; if (t1 > NP) t1 = NP;
        const double TWO_PI = 6.283185307179586476925286766559;
        double base = -TWO_PI / (double)NP;
        // step rotation r = e^{-2pi i k / NP}
        double rr, ri;
        sincos(base * (double)k, &ri, &rr);
        // start phase p = e^{-2pi i k t0 / NP}
        int m0 = (k * t0) % NP;   // k*t0 <= 1998*3750 fits int32
        double pr, pi;
        sincos(base * (double)m0, &pi, &pr);
        for (int t = t0; t < t1; ++t) {
            double kv = (double)lks[t];
            sr = fma(kv, pr, sr);
            si = fma(kv, pi, si);
            double nr = pr * rr - pi * ri;
            double ni = pr * ri + pi * rr;
            pr = nr; pi = ni;
        }
    }
    red[tid] = make_double2(sr, si);
    __syncthreads();
    for (int s = 128; s >= 16; s >>= 1) {
        if (tid < s) {
            red[tid].x += red[tid + s].x;
            red[tid].y += red[tid + s].y;
        }
        __syncthreads();
    }
    if (tc == 0 && k < KHALF)
        S[b * NP + k] = make_float2((float)red[tid].x, (float)red[tid].y);
}

// K4: per (b,w): 20-term windowed DFT for k<KHALF via rotation recurrence,
// M, M1=|S-W|, strong mask, result (mirrored write), row max
__global__ __launch_bounds__(256) void window_kernel(
        const float* __restrict__ ks, const float2* __restrict__ tw,
        const float2* __restrict__ S, const float* __restrict__ alpha_p,
        float* __restrict__ out, unsigned int* __restrict__ rmax) {
    __shared__ float red[256];
    __shared__ float ksw[WIN];
    int b = blockIdx.y;
    int w = blockIdx.x;
    int start = w * STEPW;
    int tid = threadIdx.x;
    if (tid < WIN) ksw[tid] = ks[b * NP + start + tid];
    __syncthreads();
    float alpha = *alpha_p;

    float Mv[8], M1v[8];
    float lmax = 0.f;
    #pragma unroll
    for (int c = 0; c < 8; ++c) {
        int k = tid + c * 256;
        float Mc = 0.f, M1c = 0.f;
        if (k < KHALF) {
            float2 r = tw[k];                       // coalesced, L2-resident
            float2 p = tw[(k * start) % NP];        // scattered, L2-resident
            float wr = 0.f, wi = 0.f;
            #pragma unroll
            for (int j = 0; j < WIN; ++j) {
                wr = fmaf(ksw[j], p.x, wr);
                wi = fmaf(ksw[j], p.y, wi);
                float nx = fmaf(p.x, r.x, -p.y * r.y);
                float ny = fmaf(p.x, r.y,  p.y * r.x);
                p.x = nx; p.y = ny;
            }
            Mc = sqrtf(wr * wr + wi * wi);
            float2 Sv = S[b * NP + k];
            float dr = Sv.x - wr, di = Sv.y - wi;
            M1c = sqrtf(dr * dr + di * di);
            lmax = fmaxf(lmax, Mc);
        }
        Mv[c] = Mc; M1v[c] = M1c;
    }
    red[tid] = lmax;
    __syncthreads();
    for (int s = 128; s > 0; s >>= 1) {
        if (tid < s) red[tid] = fmaxf(red[tid], red[tid + s]);
        __syncthreads();
    }
    float cutoff = red[0] * alpha;
    __syncthreads();

    float rlmax = 0.f;
    size_t base = ((size_t)(b * NW + w)) * NP;
    #pragma unroll
    for (int c = 0; c < 8; ++c) {
        int k = tid + c * 256;
        if (k < KHALF) {
            float M = Mv[c];
            float res = 0.f;
            if (M > cutoff) res = fminf(M, M1v[c] * M);  // strong=1 path; else 0
            out[base + k] = res;
            if (k > 0) out[base + NP - k] = res;         // Hermitian mirror
            rlmax = fmaxf(rlmax, res);
        }
    }
    red[tid] = rlmax;
    __syncthreads();
    for (int s = 128; s > 0; s >>= 1) {
        if (tid < s) red[tid] = fmaxf(red[tid], red[tid + s]);
        __syncthreads();
    }
    if (tid == 0) atomicMax(&rmax[b], __float_as_uint(red[0]));
}

// K5: final threshold result * (result > beta*max); read half, write mirrored
__global__ void thresh_kernel(float* __restrict__ out,
                              const unsigned int* __restrict__ rmax,
                              const float* __restrict__ beta_p) {
    int b = blockIdx.z;
    int w = blockIdx.y;
    int k = blockIdx.x * 256 + threadIdx.x;
    if (k < KHALF) {
        float thr = (*beta_p) * __uint_as_float(rmax[b]);
        size_t base = ((size_t)(b * NW + w)) * NP;
        float v = out[base + k];
        if (v != 0.0f && !(v > thr)) {
            out[base + k] = 0.f;
            if (k > 0) out[base + NP - k] = 0.f;
        }
    }
}

extern "C" void kernel_launch(void* const* d_in, const int* in_sizes, int n_in,
                              void* d_out, int out_size, void* d_ws, size_t ws_size,
                              hipStream_t stream) {
    const float* sig       = (const float*)d_in[0];
    const float* alpha_p   = (const float*)d_in[1];
    const float* beta_p    = (const float*)d_in[2];
    const float* gamma_raw = (const float*)d_in[3];
    char* ws = (char*)d_ws;
    float*        ks   = (float*)(ws + 0);
    float2*       tw   = (float2*)(ws + 64000);
    float2*       S    = (float2*)(ws + 96000);
    unsigned int* rmax = (unsigned int*)(ws + 224000);
    float* out = (float*)d_out;

    hipLaunchKernelGGL(prep_kernel,    dim3(BATCH),     dim3(256), 0, stream, sig, gamma_raw, ks);
    hipLaunchKernelGGL(twiddle_kernel, dim3(16),        dim3(256), 0, stream, tw, rmax);
    hipLaunchKernelGGL(dft_kernel,     dim3(125, BATCH),dim3(256), 0, stream, ks, (double2*)ws, S);
    hipLaunchKernelGGL(window_kernel,  dim3(NW, BATCH), dim3(256), 0, stream, ks, tw, S, alpha_p, out, rmax);
    hipLaunchKernelGGL(thresh_kernel,  dim3(8, NW, BATCH), dim3(256), 0, stream, out, rmax, beta_p);
}